// Round 5
// baseline (12.878 us; speedup 1.0000x reference)
//
#include <hip/hip_runtime.h>

// DAGGenome.get_active_mask — reachability from node 0 along left/right edges.
// Reference: N-step scan with scatter-.set (duplicate indices: LAST wins).
// Equivalent fixpoint: R[c] |= R[lp[c]] | R[rp[c]] where
//   lp[c] = max{ i : left[i]==c && 0<=left[i]<N }  (per-channel last parent).
// Output dtype: bool mask -> harness reads d_out as INT32 (0/1).
//
// R5 design (critical path = sweeps x (barrier + scattered LDS latency)):
//  - LAGGED termination: at top of sweep e read flags[e-1] (finalized by the
//    barrier just crossed), overlap with sweep loads, break BEFORE the
//    barrier when 0. Monotone => flags[e-1]==0 means state converged and
//    sweep e found nothing; uniform break is safe. Removes the dependent
//    flag read (~50ns LDS latency) from every sweep.
//  - root written during init phase -> parent-pull needs no trailing barrier.
//  - own-reach tracked in rmask register -> output from registers, no final
//    barrier, no LDS re-reads. Strided i=tid+k*NT -> lane-coalesced stores.
//  - pend bitmask + sentinel reach[SENT]==0 -> branchless 2 byte-reads per
//    pending node; parentless nodes dead at setup.

#define NN   8192
#define NT   512
#define PER  (NN / NT)          // 16 nodes per thread, strided
#define SENT NN                 // sentinel: reach[SENT] stays 0 forever
#define MAXE 512                // epoch cap (== NT so flags init is 1 store/thread)

__global__ __launch_bounds__(NT) void dag_reach_kernel(
    const int* __restrict__ left,
    const int* __restrict__ right,
    int* __restrict__ out)
{
    __shared__ int           lpI[NN + 1];
    __shared__ int           rpI[NN + 1];
    __shared__ unsigned char reach[NN + 4];   // +4: sentinel dword
    __shared__ int           flags[MAXE];

    const int tid = threadIdx.x;

    // ---- global loads first (overlap latency with LDS init) ----
    int lv[PER], rv[PER];
    #pragma unroll
    for (int k = 0; k < PER; ++k) {
        const int i = tid + k * NT;
        lv[k] = left[i];
        rv[k] = right[i];
    }

    // ---- init LDS (root set here too; no extra barrier later) ----
    #pragma unroll
    for (int k = 0; k < PER; ++k) {
        const int i = tid + k * NT;
        lpI[i] = -1;
        rpI[i] = -1;
    }
    int* reach32 = (int*)reach;
    #pragma unroll
    for (int k = 0; k < (NN / 4) / NT; ++k)   // 2048 dwords / 512 thr = 4
        reach32[tid + k * NT] = 0;
    if (tid == 0) {
        reach32[NN / 4] = 0;   // sentinel bytes reach[NN..NN+3]
        lpI[SENT] = -1;
        rpI[SENT] = -1;
        reach[0] = 1;          // root (after zeroing by same thread)
    }
    flags[tid] = 0;            // MAXE == NT
    __syncthreads();

    // ---- last-wins scatter: MAX parent index per target, both channels ----
    #pragma unroll
    for (int k = 0; k < PER; ++k) {
        const int i = tid + k * NT;
        const int l = lv[k];
        const int r = rv[k];
        if ((unsigned)l < (unsigned)NN) atomicMax(&lpI[l], i);
        if ((unsigned)r < (unsigned)NN) atomicMax(&rpI[r], i);
    }
    __syncthreads();

    // ---- pull parents into registers (sentinel-mapped); build pend mask ----
    // (reads only; reach/root already initialized pre-barrier -> no barrier
    //  needed before sweep 0)
    int lp[PER], rp[PER];
    unsigned pend = 0, rmask = 0;
    #pragma unroll
    for (int k = 0; k < PER; ++k) {
        const int i = tid + k * NT;
        const int a = lpI[i];
        const int b = rpI[i];
        lp[k] = (a < 0) ? SENT : a;
        rp[k] = (b < 0) ? SENT : b;
        if ((a >= 0 || b >= 0) && i != 0) pend |= (1u << k);  // parentless = dead
    }
    if (tid == 0) rmask |= 1u;    // node 0 (tid 0, k 0) is the root

    // ---- fixpoint sweeps: 1 barrier/sweep, lagged termination check ----
    for (int e = 0; ; ++e) {
        int fprev = 1;
        if (e > 0) fprev = flags[e - 1];   // overlapped LDS read (finalized)

        if (pend) {
            int prog = 0;
            #pragma unroll
            for (int k = 0; k < PER; ++k) {
                if (pend & (1u << k)) {
                    if (reach[lp[k]] | reach[rp[k]]) {   // 2 scattered byte reads
                        reach[tid + k * NT] = 1;
                        rmask |= (1u << k);
                        pend  &= ~(1u << k);
                        prog = 1;
                    }
                }
            }
            if (prog) flags[e] = 1;   // plain store, same value from all writers
        }

        if (fprev == 0) break;        // uniform: converged, this sweep found nothing
        if (e >= MAXE - 2) break;     // safety cap
        __syncthreads();
    }

    // ---- output int32 0/1 from registers (no barrier needed) ----
    #pragma unroll
    for (int k = 0; k < PER; ++k) {
        out[tid + k * NT] = (int)((rmask >> k) & 1u);
    }
}

extern "C" void kernel_launch(void* const* d_in, const int* in_sizes, int n_in,
                              void* d_out, int out_size, void* d_ws, size_t ws_size,
                              hipStream_t stream) {
    // setup_inputs order: thresholds, rules_left, rules_right, binary_ops, left, right
    const int* left  = (const int*)d_in[4];
    const int* right = (const int*)d_in[5];
    int* out = (int*)d_out;

    dag_reach_kernel<<<1, NT, 0, stream>>>(left, right, out);
}